// Round 5
// baseline (1068.744 us; speedup 1.0000x reference)
//
#include <hip/hip_runtime.h>
#include <hip/hip_bf16.h>
#include <math.h>

// ---------------------------------------------------------------------------
// Round 5: conservative rebuild from validated components.
//   k0a/k0b: G = W2b W2b^T (bf16-rounded W2)       [round-2 verbatim, passed]
//   k0c:     wbar/hb/scal                           [round-2 verbatim, passed]
//   k0e:     W2t = transpose(bf16(W2))              [round-2 verbatim, passed]
//   k1:      f32 GEMM1, FULL k=0..4095 ascending fmaf chain per output
//            (bitwise == round-1's passing order). 512 blocks = 256 rowblocks
//            x 2 colblocks (adjacent bids share the x rowslice in L2).
//            Raw acc -> qpart f32, ALIASED onto featsb region (row-aligned).
//   k1c:     tanh(acc+b1) + quantum circuit (validated verbatim) -> featsb.
//   k1r/k1b: analytic LN stats (validated round-2 stats block) -> muinv.
//   k2:      round-2 verbatim (bf16 MFMA, fragment-direct, scalar epilogue).
// ws footprint: 6,489,120 B == round 2's proven-safe footprint.
// ---------------------------------------------------------------------------

#define B_ROWS 16384
#define D_DIM  4096
#define LN_EPS 1e-5f

typedef unsigned short ushortT;
typedef short bf16x8 __attribute__((ext_vector_type(8)));
typedef float f32x4 __attribute__((ext_vector_type(4)));

// ---- ws byte offsets (== round 2 layout; qpart aliases feats) ----
#define G_OFF      0u           // 128*128 f32   = 65536
#define GPART_OFF  65536u       // 16*16384 f32  = 1048576 (dead after k0b)
#define WBAR_OFF   1114112u     // 128 f32
#define HB_OFF     1114624u     // 128 f32
#define SCAL_OFF   1115136u     // 8 f32
#define MUINV_OFF  1115168u     // 16384 float2  = 131072
#define FEATS_OFF  1246240u     // 16384 rows x 256B: qpart f32[64] then bf16[128]
#define W2T_OFF    5440544u     // 4096*128 bf16  = 1048576
// total 6,489,120 B

__device__ __forceinline__ ushortT f2b(float v) {
  __hip_bfloat16 h = __float2bfloat16(v);
  return *(ushortT*)&h;
}
__device__ __forceinline__ float b2f(ushortT u) {
  __hip_bfloat16 h;
  *(ushortT*)&h = u;
  return __bfloat162float(h);
}
__device__ __forceinline__ float rndbf(float v) { return b2f(f2b(v)); }

#define FMA16(ACC, AV, BV)                                   \
  ACC[0][0] = fmaf(AV.x, BV.x, ACC[0][0]);                   \
  ACC[0][1] = fmaf(AV.x, BV.y, ACC[0][1]);                   \
  ACC[0][2] = fmaf(AV.x, BV.z, ACC[0][2]);                   \
  ACC[0][3] = fmaf(AV.x, BV.w, ACC[0][3]);                   \
  ACC[1][0] = fmaf(AV.y, BV.x, ACC[1][0]);                   \
  ACC[1][1] = fmaf(AV.y, BV.y, ACC[1][1]);                   \
  ACC[1][2] = fmaf(AV.y, BV.z, ACC[1][2]);                   \
  ACC[1][3] = fmaf(AV.y, BV.w, ACC[1][3]);                   \
  ACC[2][0] = fmaf(AV.z, BV.x, ACC[2][0]);                   \
  ACC[2][1] = fmaf(AV.z, BV.y, ACC[2][1]);                   \
  ACC[2][2] = fmaf(AV.z, BV.z, ACC[2][2]);                   \
  ACC[2][3] = fmaf(AV.z, BV.w, ACC[2][3]);                   \
  ACC[3][0] = fmaf(AV.w, BV.x, ACC[3][0]);                   \
  ACC[3][1] = fmaf(AV.w, BV.y, ACC[3][1]);                   \
  ACC[3][2] = fmaf(AV.w, BV.z, ACC[3][2]);                   \
  ACC[3][3] = fmaf(AV.w, BV.w, ACC[3][3]);

// ---------------- K0a: Gpart from bf16-rounded W2
__global__ __launch_bounds__(256) void k0a(const float* __restrict__ W2,
                                           float* __restrict__ gpart) {
  __shared__ float wbt[32][132];
  const int tid = threadIdx.x;
  const int ac = blockIdx.x & 3;
  const int kp = blockIdx.x >> 2;
  const int kbase = kp * 256;
  const int ag = tid >> 5, a0 = ag * 4;
  const int bg = tid & 31, b0 = bg * 4;
  const int sb = tid >> 1;
  const int sk = (tid & 1) * 16;
  float acc[4][4] = {};
  for (int sub = 0; sub < 8; ++sub) {
    const int k0 = kbase + sub * 32;
    const float* wp = W2 + (size_t)sb * D_DIM + k0 + sk;
#pragma unroll
    for (int j4 = 0; j4 < 4; ++j4) {
      float4 v = *(const float4*)(wp + j4 * 4);
      wbt[sk + j4 * 4 + 0][sb] = rndbf(v.x);
      wbt[sk + j4 * 4 + 1][sb] = rndbf(v.y);
      wbt[sk + j4 * 4 + 2][sb] = rndbf(v.z);
      wbt[sk + j4 * 4 + 3][sb] = rndbf(v.w);
    }
    __syncthreads();
#pragma unroll 8
    for (int k = 0; k < 32; ++k) {
      float4 av = *(const float4*)&wbt[k][ac * 32 + a0];
      float4 bv = *(const float4*)&wbt[k][b0];
      FMA16(acc, av, bv)
    }
    __syncthreads();
  }
  float* gp = gpart + (size_t)kp * 16384 + (size_t)(ac * 32 + a0) * 128 + b0;
#pragma unroll
  for (int i = 0; i < 4; ++i) {
    float4 v;
    v.x = acc[i][0]; v.y = acc[i][1]; v.z = acc[i][2]; v.w = acc[i][3];
    *(float4*)(gp + (size_t)i * 128) = v;
  }
}

// ---------------- K0b: reduce partials -> G
__global__ __launch_bounds__(256) void k0b(const float* __restrict__ gpart,
                                           float* __restrict__ G) {
  const int e = blockIdx.x * 256 + threadIdx.x;
  float s = 0.f;
#pragma unroll
  for (int p = 0; p < 16; ++p) s += gpart[(size_t)p * 16384 + e];
  G[e] = s;
}

// ---------------- K0c: wbar, hb (bf16-rounded W2), sumb, sum b2^2
__global__ __launch_bounds__(256) void k0c(const float* __restrict__ W2,
                                           const float* __restrict__ b2,
                                           float* __restrict__ wbar,
                                           float* __restrict__ hb,
                                           float* __restrict__ scal) {
  __shared__ float r1[256], r2[256];
  const int a = blockIdx.x, t = threadIdx.x;
  float s1 = 0.f, s2 = 0.f;
  if (a < 128) {
    const float* wp = W2 + (size_t)a * D_DIM;
    for (int j = t; j < D_DIM; j += 256) {
      float w = rndbf(wp[j]);
      s1 += w; s2 = fmaf(w, b2[j], s2);
    }
  } else {
    for (int j = t; j < D_DIM; j += 256) { float b = b2[j]; s1 += b; s2 = fmaf(b, b, s2); }
  }
  r1[t] = s1; r2[t] = s2;
  __syncthreads();
  for (int s = 128; s > 0; s >>= 1) {
    if (t < s) { r1[t] += r1[t + s]; r2[t] += r2[t + s]; }
    __syncthreads();
  }
  if (t == 0) {
    if (a < 128) { wbar[a] = r1[0]; hb[a] = r2[0]; }
    else         { scal[0] = r1[0]; scal[1] = r2[0]; }
  }
}

// ---------------- K0e: W2t[n][k] = bf16(W2[k][n])   (4096 x 128 bf16)
__global__ __launch_bounds__(256) void k0e(const float* __restrict__ W2,
                                           ushortT* __restrict__ W2t) {
  __shared__ ushortT tile[32][136];
  const int t = threadIdx.x;
  const int j0 = blockIdx.x * 32;
#pragma unroll
  for (int p = 0; p < 4; ++p) {
    const int a = p * 32 + (t >> 3);
    const int jc = (t & 7) * 4;
    float4 v = *(const float4*)&W2[(size_t)a * D_DIM + j0 + jc];
    tile[jc + 0][a] = f2b(v.x);
    tile[jc + 1][a] = f2b(v.y);
    tile[jc + 2][a] = f2b(v.z);
    tile[jc + 3][a] = f2b(v.w);
  }
  __syncthreads();
  const int j = t >> 3;
  const int a0 = (t & 7) * 16;
  uint4 u0 = *(const uint4*)&tile[j][a0];
  uint4 u1 = *(const uint4*)&tile[j][a0 + 8];
  *(uint4*)&W2t[(size_t)(j0 + j) * 128 + a0] = u0;
  *(uint4*)&W2t[(size_t)(j0 + j) * 128 + a0 + 8] = u1;
}

// ---------------- K1: f32 GEMM1, full-K ascending chain (== round 1 order)
// grid 512: cb = bid&1 (32 cols), rb = bid>>1 (64 rows). 256 thr = 4 waves.
// lane = row; wave wid owns cols cb*32 + wid*8 .. +7. W1 via scalar loads.
// Writes raw acc (f32) to qpart[row][c]  (qpart aliases feats region).
__global__ __launch_bounds__(256) void k1(const float* __restrict__ x,
                                          const float* __restrict__ W1,
                                          float* __restrict__ qpart) {
  __shared__ float xs[64][69];  // [k][row], stride 69 breaks write conflicts
  const int tid = threadIdx.x;
  const int bid = blockIdx.x;
  const int cb = bid & 1;
  const int rb = bid >> 1;
  const size_t row0 = (size_t)rb * 64;
  const int lane = tid & 63;
  const int wid = tid >> 6;
  const int c0 = __builtin_amdgcn_readfirstlane(cb * 32 + wid * 8);
  float acc[8] = {};
  const int sr = tid >> 2;         // staging row 0..63
  const int sq = (tid & 3) * 16;   // staging k offset
  float4 xr[4];
  {
    const float* xp = x + (row0 + sr) * D_DIM + sq;
#pragma unroll
    for (int i = 0; i < 4; ++i) xr[i] = *(const float4*)(xp + i * 4);
  }
  for (int t = 0; t < 64; ++t) {
    __syncthreads();  // previous tile fully consumed
#pragma unroll
    for (int i = 0; i < 4; ++i) {
      xs[sq + i * 4 + 0][sr] = xr[i].x;
      xs[sq + i * 4 + 1][sr] = xr[i].y;
      xs[sq + i * 4 + 2][sr] = xr[i].z;
      xs[sq + i * 4 + 3][sr] = xr[i].w;
    }
    __syncthreads();
    if (t < 63) {
      const float* xp = x + (row0 + sr) * D_DIM + (t + 1) * 64 + sq;
#pragma unroll
      for (int i = 0; i < 4; ++i) xr[i] = *(const float4*)(xp + i * 4);
    }
    const int kg = t * 64;
#pragma unroll 8
    for (int k = 0; k < 64; ++k) {
      const float xv = xs[k][lane];
      const float* wrow = W1 + (size_t)(kg + k) * 128 + c0;  // wave-uniform
#pragma unroll
      for (int j = 0; j < 8; ++j)
        acc[j] = fmaf(xv, wrow[j], acc[j]);
    }
  }
  float* qp = qpart + ((size_t)(row0 + lane)) * 64 + c0;
  float4 v0, v1;
  v0.x = acc[0]; v0.y = acc[1]; v0.z = acc[2]; v0.w = acc[3];
  v1.x = acc[4]; v1.y = acc[5]; v1.z = acc[6]; v1.w = acc[7];
  *(float4*)qp = v0;
  *(float4*)(qp + 4) = v1;
}

// ---------------- K1c: tanh(acc+b1) + quantum circuit -> feats bf16
// qpart and featsb alias the same region row-for-row: all qpart reads for
// this block's rows complete (via barrier) before featsb writes begin.
__global__ __launch_bounds__(256) void k1c(const float* __restrict__ qpart,
                                           const float* __restrict__ b1,
                                           ushortT* __restrict__ featsb) {
  __shared__ float qs[64 * 69];
  const int tid = threadIdx.x;
  const size_t row0 = (size_t)blockIdx.x * 64;
  {
    const int r = tid >> 2, c16 = (tid & 3) * 16;
    const float* qp = qpart + (row0 + r) * 64 + c16;
#pragma unroll
    for (int m = 0; m < 4; ++m) {
      const int c = c16 + 4 * m;
      float4 v = *(const float4*)(qp + 4 * m);
      qs[r * 69 + c + 0] = tanhf(v.x + b1[c + 0]);
      qs[r * 69 + c + 1] = tanhf(v.y + b1[c + 1]);
      qs[r * 69 + c + 2] = tanhf(v.z + b1[c + 2]);
      qs[r * 69 + c + 3] = tanhf(v.w + b1[c + 3]);
    }
  }
  __syncthreads();
  if (tid < 64) {
    const int r = tid;
    ushortT* frow = featsb + (row0 + r) * 128;
    const float PI_F = 3.14159274101257324f;
    const float IS2 = 0.707106769084930420f;
    bool swp = false;
    for (int j = 0; j < 32; ++j) {
      float th = qs[r * 69 + 2 * j] * PI_F;
      float ph = qs[r * 69 + 2 * j + 1] * PI_F;
      float hf = 0.5f * th;
      float chf = cosf(hf), shf = sinf(hf);
      float cp = cosf(ph), sp = sinf(ph);
      float ar = chf, ai = 0.0f;
      float br = shf * cp, bi = shf * sp;
      if ((j & 1) == 0) {
        float t1r = (ar + br) * IS2, t1i = (ai + bi) * IS2;
        float t2r = (ar - br) * IS2, t2i = (ai - bi) * IS2;
        ar = t1r; ai = t1i; br = t2r; bi = t2i;
      }
      if (swp) { float t = ar; ar = br; br = t; t = ai; ai = bi; bi = t; }
      ushort4 o;
      o.x = f2b(ar); o.y = f2b(ai); o.z = f2b(br); o.w = f2b(bi);
      *(ushort4*)&frow[4 * j] = o;
      swp = sqrtf(fmaf(br, br, bi * bi)) > 0.5f;
    }
  }
}

// ---------------- K1b: analytic LN stats per row -> muinv
__global__ __launch_bounds__(256) void k1b(const ushortT* __restrict__ featsb,
                                           const float* __restrict__ G,
                                           const float* __restrict__ wbar,
                                           const float* __restrict__ hb,
                                           const float* __restrict__ scal,
                                           float2* __restrict__ muinv) {
  __shared__ float ftr[128 * 68];
  __shared__ float gbuf[32 * 128];
  __shared__ float e2red[64 * 4];
  const int tid = threadIdx.x;
  const size_t row0 = (size_t)blockIdx.x * 64;
  {
    const int r = tid >> 2;
    const int ks = (tid & 3) * 32;
    const ushortT* fp = featsb + (row0 + r) * 128 + ks;
#pragma unroll
    for (int i = 0; i < 4; ++i) {
      ushort4 u0 = *(const ushort4*)(fp + i * 8);
      ushort4 u1 = *(const ushort4*)(fp + i * 8 + 4);
      ftr[(ks + i * 8 + 0) * 68 + r] = b2f(u0.x);
      ftr[(ks + i * 8 + 1) * 68 + r] = b2f(u0.y);
      ftr[(ks + i * 8 + 2) * 68 + r] = b2f(u0.z);
      ftr[(ks + i * 8 + 3) * 68 + r] = b2f(u0.w);
      ftr[(ks + i * 8 + 4) * 68 + r] = b2f(u1.x);
      ftr[(ks + i * 8 + 5) * 68 + r] = b2f(u1.y);
      ftr[(ks + i * 8 + 6) * 68 + r] = b2f(u1.z);
      ftr[(ks + i * 8 + 7) * 68 + r] = b2f(u1.w);
    }
  }
  __syncthreads();
  const int sr = tid >> 2;
  const int sp = tid & 3;
  float e2p = 0.f, mup = 0.f, hbp = 0.f;
  for (int chk = 0; chk < 4; ++chk) {
    __syncthreads();
    {
      const int al = tid >> 3;
      const int bo = (tid & 7) * 16;
      const float* gp = G + (size_t)(chk * 32 + al) * 128 + bo;
#pragma unroll
      for (int j4 = 0; j4 < 4; ++j4)
        *(float4*)(gbuf + al * 128 + bo + j4 * 4) = *(const float4*)(gp + j4 * 4);
    }
    __syncthreads();
    float vacc[32];
#pragma unroll
    for (int i = 0; i < 32; ++i) vacc[i] = 0.f;
    for (int al = 0; al < 32; ++al) {
      const int a = chk * 32 + al;
      const float fa = ftr[a * 68 + sr];
      const float* grow = gbuf + al * 128 + sp * 32;
#pragma unroll
      for (int t8 = 0; t8 < 8; ++t8) {
        float4 gv = *(const float4*)(grow + t8 * 4);
        vacc[t8 * 4 + 0] = fmaf(fa, gv.x, vacc[t8 * 4 + 0]);
        vacc[t8 * 4 + 1] = fmaf(fa, gv.y, vacc[t8 * 4 + 1]);
        vacc[t8 * 4 + 2] = fmaf(fa, gv.z, vacc[t8 * 4 + 2]);
        vacc[t8 * 4 + 3] = fmaf(fa, gv.w, vacc[t8 * 4 + 3]);
      }
      if (sp == 0) { mup = fmaf(fa, wbar[a], mup); hbp = fmaf(fa, hb[a], hbp); }
    }
#pragma unroll
    for (int bl = 0; bl < 32; ++bl)
      e2p = fmaf(vacc[bl], ftr[(sp * 32 + bl) * 68 + sr], e2p);
  }
  e2red[sr * 4 + sp] = e2p;
  __syncthreads();
  if (sp == 0) {
    float e2 = e2red[sr * 4 + 0] + e2red[sr * 4 + 1] + e2red[sr * 4 + 2] + e2red[sr * 4 + 3];
    e2 = fmaf(2.0f, hbp, e2) + scal[1];
    const float mu = (mup + scal[0]) * (1.0f / D_DIM);
    const float var = e2 * (1.0f / D_DIM) - mu * mu;
    float2 mi2;
    mi2.x = mu;
    mi2.y = 1.0f / sqrtf(var + LN_EPS);
    muinv[row0 + sr] = mi2;
  }
}

// ---------------- K2: bf16 MFMA GEMM2 + LN + residual (round-2 verbatim)
__global__ __launch_bounds__(256) void k2(const ushortT* __restrict__ featsb,
                                          const ushortT* __restrict__ W2t,
                                          const float* __restrict__ b2,
                                          const float* __restrict__ gam,
                                          const float* __restrict__ bet,
                                          const float* __restrict__ x,
                                          const float2* __restrict__ muinv,
                                          float* __restrict__ out) {
  const int bid = blockIdx.x;
  const int swz = (bid & 7) * 512 + (bid >> 3);
  const int mblk = swz >> 5, nblk = swz & 31;
  const size_t row0 = (size_t)mblk * 128;
  const size_t col0 = (size_t)nblk * 128;
  const int tid = threadIdx.x;
  const int wid = tid >> 6, lane = tid & 63;
  const int wm = wid >> 1, wn = wid & 1;
  const int lr = lane & 15, lg = lane >> 4;
  f32x4 acc[4][4];
#pragma unroll
  for (int i = 0; i < 4; ++i)
#pragma unroll
    for (int j = 0; j < 4; ++j) acc[i][j] = (f32x4){0.f, 0.f, 0.f, 0.f};
  const ushortT* aBase = featsb + (row0 + wm * 64 + lr) * 128 + lg * 8;
  const ushortT* bBase = W2t + (col0 + wn * 64 + lr) * 128 + lg * 8;
#pragma unroll
  for (int ks = 0; ks < 4; ++ks) {
    bf16x8 a[4], b[4];
#pragma unroll
    for (int mi = 0; mi < 4; ++mi)
      a[mi] = *(const bf16x8*)(aBase + (size_t)mi * 16 * 128 + ks * 32);
#pragma unroll
    for (int ni = 0; ni < 4; ++ni)
      b[ni] = *(const bf16x8*)(bBase + (size_t)ni * 16 * 128 + ks * 32);
#pragma unroll
    for (int mi = 0; mi < 4; ++mi)
#pragma unroll
      for (int ni = 0; ni < 4; ++ni)
        acc[mi][ni] = __builtin_amdgcn_mfma_f32_16x16x32_bf16(a[mi], b[ni], acc[mi][ni], 0, 0, 0);
  }
  float b2c[4], gc[4], btc[4];
#pragma unroll
  for (int ni = 0; ni < 4; ++ni) {
    const size_t col = col0 + wn * 64 + ni * 16 + lr;
    b2c[ni] = b2[col];
    gc[ni] = gam[col];
    btc[ni] = bet[col];
  }
#pragma unroll
  for (int mi = 0; mi < 4; ++mi) {
#pragma unroll
    for (int j = 0; j < 4; ++j) {
      const size_t row = row0 + wm * 64 + mi * 16 + lg * 4 + j;
      const float2 mi2 = muinv[row];
      const float mu = mi2.x, inv = mi2.y;
      const float* xrow = x + row * D_DIM;
      float* orow = out + row * D_DIM;
#pragma unroll
      for (int ni = 0; ni < 4; ++ni) {
        const size_t col = col0 + wn * 64 + ni * 16 + lr;
        const float val = acc[mi][ni][j];
        const float y = fmaf((val + b2c[ni] - mu) * inv, gc[ni], btc[ni]) + xrow[col];
        orow[col] = y;
      }
    }
  }
}

extern "C" void kernel_launch(void* const* d_in, const int* in_sizes, int n_in,
                              void* d_out, int out_size, void* d_ws, size_t ws_size,
                              hipStream_t stream) {
  const float* x = (const float*)d_in[0];
  const float* W1 = (const float*)d_in[1];
  const float* b1 = (const float*)d_in[2];
  const float* W2 = (const float*)d_in[3];
  const float* b2 = (const float*)d_in[4];
  const float* gam = (const float*)d_in[5];
  const float* bet = (const float*)d_in[6];
  float* out = (float*)d_out;
  char* ws = (char*)d_ws;
  float* G = (float*)(ws + G_OFF);
  float* gpart = (float*)(ws + GPART_OFF);
  float* wbar = (float*)(ws + WBAR_OFF);
  float* hbv = (float*)(ws + HB_OFF);
  float* scal = (float*)(ws + SCAL_OFF);
  float2* muinv = (float2*)(ws + MUINV_OFF);
  float* qpart = (float*)(ws + FEATS_OFF);       // aliases featsb (row-aligned)
  ushortT* featsb = (ushortT*)(ws + FEATS_OFF);
  ushortT* W2t = (ushortT*)(ws + W2T_OFF);

  hipLaunchKernelGGL(k0a, dim3(64), dim3(256), 0, stream, W2, gpart);
  hipLaunchKernelGGL(k0b, dim3(64), dim3(256), 0, stream, gpart, G);
  hipLaunchKernelGGL(k0c, dim3(129), dim3(256), 0, stream, W2, b2, wbar, hbv, scal);
  hipLaunchKernelGGL(k0e, dim3(128), dim3(256), 0, stream, W2, W2t);
  hipLaunchKernelGGL(k1, dim3(512), dim3(256), 0, stream, x, W1, qpart);
  hipLaunchKernelGGL(k1c, dim3(B_ROWS / 64), dim3(256), 0, stream, qpart, b1, featsb);
  hipLaunchKernelGGL(k1b, dim3(B_ROWS / 64), dim3(256), 0, stream,
                     featsb, G, wbar, hbv, scal, muinv);
  hipLaunchKernelGGL(k2, dim3(4096), dim3(256), 0, stream,
                     featsb, W2t, b2, gam, bet, x, muinv, out);
}

// Round 7
// 955.168 us; speedup vs baseline: 1.1189x; 1.1189x over previous
//
#include <hip/hip_runtime.h>
#include <hip/hip_bf16.h>
#include <math.h>

// ---------------------------------------------------------------------------
// Round 7: BISECTION round = round 5 (PASSED) + exactly ONE delta: new k1.
//   k0a/k0b/k0c/k0e: validated verbatim (rounds 2/5).
//   k1:      NEW: f32 GEMM1, full k=0..4095 ascending fmaf chain per output
//            (bitwise == round 5's q). TN=4/thread, grid 1024 (4 waves/SIMD),
//            W1 via LDS broadcast (no s_load chain), XCD-grouped col-blocks.
//   k1c:     round-5 verbatim (tanh + circuit -> featsb).
//   k1b:     round-5 verbatim (analytic LN stats -> muinv).
//   k2:      round-5 verbatim (bf16 MFMA, fragment-direct, scalar epilogue).
// ws footprint: 6,489,120 B (proven-safe).
// ---------------------------------------------------------------------------

#define B_ROWS 16384
#define D_DIM  4096
#define LN_EPS 1e-5f

typedef unsigned short ushortT;
typedef short bf16x8 __attribute__((ext_vector_type(8)));
typedef float f32x4 __attribute__((ext_vector_type(4)));

// ---- ws byte offsets (== round 5 layout; qpart aliases feats) ----
#define G_OFF      0u           // 128*128 f32   = 65536
#define GPART_OFF  65536u       // 16*16384 f32  = 1048576 (dead after k0b)
#define WBAR_OFF   1114112u     // 128 f32
#define HB_OFF     1114624u     // 128 f32
#define SCAL_OFF   1115136u     // 8 f32
#define MUINV_OFF  1115168u     // 16384 float2  = 131072
#define FEATS_OFF  1246240u     // 16384 rows x 256B: qpart f32[64] -> bf16[128]
#define W2T_OFF    5440544u     // 4096*128 bf16  = 1048576
// total 6,489,120 B

__device__ __forceinline__ ushortT f2b(float v) {
  __hip_bfloat16 h = __float2bfloat16(v);
  return *(ushortT*)&h;
}
__device__ __forceinline__ float b2f(ushortT u) {
  __hip_bfloat16 h;
  *(ushortT*)&h = u;
  return __bfloat162float(h);
}
__device__ __forceinline__ float rndbf(float v) { return b2f(f2b(v)); }

#define FMA16(ACC, AV, BV)                                   \
  ACC[0][0] = fmaf(AV.x, BV.x, ACC[0][0]);                   \
  ACC[0][1] = fmaf(AV.x, BV.y, ACC[0][1]);                   \
  ACC[0][2] = fmaf(AV.x, BV.z, ACC[0][2]);                   \
  ACC[0][3] = fmaf(AV.x, BV.w, ACC[0][3]);                   \
  ACC[1][0] = fmaf(AV.y, BV.x, ACC[1][0]);                   \
  ACC[1][1] = fmaf(AV.y, BV.y, ACC[1][1]);                   \
  ACC[1][2] = fmaf(AV.y, BV.z, ACC[1][2]);                   \
  ACC[1][3] = fmaf(AV.y, BV.w, ACC[1][3]);                   \
  ACC[2][0] = fmaf(AV.z, BV.x, ACC[2][0]);                   \
  ACC[2][1] = fmaf(AV.z, BV.y, ACC[2][1]);                   \
  ACC[2][2] = fmaf(AV.z, BV.z, ACC[2][2]);                   \
  ACC[2][3] = fmaf(AV.z, BV.w, ACC[2][3]);                   \
  ACC[3][0] = fmaf(AV.w, BV.x, ACC[3][0]);                   \
  ACC[3][1] = fmaf(AV.w, BV.y, ACC[3][1]);                   \
  ACC[3][2] = fmaf(AV.w, BV.z, ACC[3][2]);                   \
  ACC[3][3] = fmaf(AV.w, BV.w, ACC[3][3]);

// ---------------- K0a: Gpart from bf16-rounded W2
__global__ __launch_bounds__(256) void k0a(const float* __restrict__ W2,
                                           float* __restrict__ gpart) {
  __shared__ float wbt[32][132];
  const int tid = threadIdx.x;
  const int ac = blockIdx.x & 3;
  const int kp = blockIdx.x >> 2;
  const int kbase = kp * 256;
  const int ag = tid >> 5, a0 = ag * 4;
  const int bg = tid & 31, b0 = bg * 4;
  const int sb = tid >> 1;
  const int sk = (tid & 1) * 16;
  float acc[4][4] = {};
  for (int sub = 0; sub < 8; ++sub) {
    const int k0 = kbase + sub * 32;
    const float* wp = W2 + (size_t)sb * D_DIM + k0 + sk;
#pragma unroll
    for (int j4 = 0; j4 < 4; ++j4) {
      float4 v = *(const float4*)(wp + j4 * 4);
      wbt[sk + j4 * 4 + 0][sb] = rndbf(v.x);
      wbt[sk + j4 * 4 + 1][sb] = rndbf(v.y);
      wbt[sk + j4 * 4 + 2][sb] = rndbf(v.z);
      wbt[sk + j4 * 4 + 3][sb] = rndbf(v.w);
    }
    __syncthreads();
#pragma unroll 8
    for (int k = 0; k < 32; ++k) {
      float4 av = *(const float4*)&wbt[k][ac * 32 + a0];
      float4 bv = *(const float4*)&wbt[k][b0];
      FMA16(acc, av, bv)
    }
    __syncthreads();
  }
  float* gp = gpart + (size_t)kp * 16384 + (size_t)(ac * 32 + a0) * 128 + b0;
#pragma unroll
  for (int i = 0; i < 4; ++i) {
    float4 v;
    v.x = acc[i][0]; v.y = acc[i][1]; v.z = acc[i][2]; v.w = acc[i][3];
    *(float4*)(gp + (size_t)i * 128) = v;
  }
}

// ---------------- K0b: reduce partials -> G
__global__ __launch_bounds__(256) void k0b(const float* __restrict__ gpart,
                                           float* __restrict__ G) {
  const int e = blockIdx.x * 256 + threadIdx.x;
  float s = 0.f;
#pragma unroll
  for (int p = 0; p < 16; ++p) s += gpart[(size_t)p * 16384 + e];
  G[e] = s;
}

// ---------------- K0c: wbar, hb (bf16-rounded W2), sumb, sum b2^2
__global__ __launch_bounds__(256) void k0c(const float* __restrict__ W2,
                                           const float* __restrict__ b2,
                                           float* __restrict__ wbar,
                                           float* __restrict__ hb,
                                           float* __restrict__ scal) {
  __shared__ float r1[256], r2[256];
  const int a = blockIdx.x, t = threadIdx.x;
  float s1 = 0.f, s2 = 0.f;
  if (a < 128) {
    const float* wp = W2 + (size_t)a * D_DIM;
    for (int j = t; j < D_DIM; j += 256) {
      float w = rndbf(wp[j]);
      s1 += w; s2 = fmaf(w, b2[j], s2);
    }
  } else {
    for (int j = t; j < D_DIM; j += 256) { float b = b2[j]; s1 += b; s2 = fmaf(b, b, s2); }
  }
  r1[t] = s1; r2[t] = s2;
  __syncthreads();
  for (int s = 128; s > 0; s >>= 1) {
    if (t < s) { r1[t] += r1[t + s]; r2[t] += r2[t + s]; }
    __syncthreads();
  }
  if (t == 0) {
    if (a < 128) { wbar[a] = r1[0]; hb[a] = r2[0]; }
    else         { scal[0] = r1[0]; scal[1] = r2[0]; }
  }
}

// ---------------- K0e: W2t[n][k] = bf16(W2[k][n])   (4096 x 128 bf16)
__global__ __launch_bounds__(256) void k0e(const float* __restrict__ W2,
                                           ushortT* __restrict__ W2t) {
  __shared__ ushortT tile[32][136];
  const int t = threadIdx.x;
  const int j0 = blockIdx.x * 32;
#pragma unroll
  for (int p = 0; p < 4; ++p) {
    const int a = p * 32 + (t >> 3);
    const int jc = (t & 7) * 4;
    float4 v = *(const float4*)&W2[(size_t)a * D_DIM + j0 + jc];
    tile[jc + 0][a] = f2b(v.x);
    tile[jc + 1][a] = f2b(v.y);
    tile[jc + 2][a] = f2b(v.z);
    tile[jc + 3][a] = f2b(v.w);
  }
  __syncthreads();
  const int j = t >> 3;
  const int a0 = (t & 7) * 16;
  uint4 u0 = *(const uint4*)&tile[j][a0];
  uint4 u1 = *(const uint4*)&tile[j][a0 + 8];
  *(uint4*)&W2t[(size_t)(j0 + j) * 128 + a0] = u0;
  *(uint4*)&W2t[(size_t)(j0 + j) * 128 + a0 + 8] = u1;
}

// ---------------- K1 (NEW, the round's single delta):
// f32 GEMM1, full-K ascending chain, TN=4, grid 1024.
// bid = 32a + 8c + d: cb = c (16-col block), rb = 8a + d  ->  the 4 blocks
// sharing a row-slice have bid == d (mod 8)  ->  same XCD  ->  x L2-shared.
// lane = row; wave w owns cols cb*16 + w*4 .. +3 (float4 LDS broadcast).
// Per-output fmaf chain ascending k 0..4095  == round 5 bitwise.
__global__ __launch_bounds__(256) void k1(const float* __restrict__ x,
                                          const float* __restrict__ W1,
                                          float* __restrict__ qpart) {
  __shared__ float xs[64][65];   // [k][row]
  __shared__ float ws1[64][20];  // [k][16 cols + pad]
  const int tid = threadIdx.x;
  const int bid = blockIdx.x;    // 1024
  const int cb = (bid >> 3) & 3;
  const int rb = (bid & 7) | ((bid >> 5) << 3);
  const size_t row0 = (size_t)rb * 64;
  const int c16 = cb * 16;
  const int lane = tid & 63;
  const int w4 = (tid >> 6) * 4;
  const int sr = tid >> 2;          // staging row / k-row 0..63
  const int sq = (tid & 3) * 16;    // x staging k offset
  const int cq = (tid & 3) * 4;     // W1 staging col offset
  float acc[4] = {};
  float4 xr[4], wr;
  {
    const float* xp = x + (row0 + sr) * D_DIM + sq;
    xr[0] = *(const float4*)(xp);
    xr[1] = *(const float4*)(xp + 4);
    xr[2] = *(const float4*)(xp + 8);
    xr[3] = *(const float4*)(xp + 12);
    wr = *(const float4*)(W1 + (size_t)sr * 128 + c16 + cq);
  }
  for (int ch = 0; ch < 64; ++ch) {
    __syncthreads();  // previous chunk fully consumed
#pragma unroll
    for (int i = 0; i < 4; ++i) {
      xs[sq + i * 4 + 0][sr] = xr[i].x;
      xs[sq + i * 4 + 1][sr] = xr[i].y;
      xs[sq + i * 4 + 2][sr] = xr[i].z;
      xs[sq + i * 4 + 3][sr] = xr[i].w;
    }
    *(float4*)&ws1[sr][cq] = wr;
    __syncthreads();
    if (ch < 63) {
      const int kn = (ch + 1) * 64;
      const float* xp = x + (row0 + sr) * D_DIM + kn + sq;
      xr[0] = *(const float4*)(xp);
      xr[1] = *(const float4*)(xp + 4);
      xr[2] = *(const float4*)(xp + 8);
      xr[3] = *(const float4*)(xp + 12);
      wr = *(const float4*)(W1 + (size_t)(kn + sr) * 128 + c16 + cq);
    }
#pragma unroll 8
    for (int k = 0; k < 64; ++k) {
      const float xv = xs[k][lane];
      const float4 wv = *(const float4*)&ws1[k][w4];
      acc[0] = fmaf(xv, wv.x, acc[0]);
      acc[1] = fmaf(xv, wv.y, acc[1]);
      acc[2] = fmaf(xv, wv.z, acc[2]);
      acc[3] = fmaf(xv, wv.w, acc[3]);
    }
  }
  float4 v;
  v.x = acc[0]; v.y = acc[1]; v.z = acc[2]; v.w = acc[3];
  *(float4*)(qpart + (row0 + lane) * 64 + c16 + w4) = v;
}

// ---------------- K1c: tanh(acc+b1) + quantum circuit -> feats bf16
// (round-5 verbatim)
__global__ __launch_bounds__(256) void k1c(const float* __restrict__ qpart,
                                           const float* __restrict__ b1,
                                           ushortT* __restrict__ featsb) {
  __shared__ float qs[64 * 69];
  const int tid = threadIdx.x;
  const size_t row0 = (size_t)blockIdx.x * 64;
  {
    const int r = tid >> 2, c16 = (tid & 3) * 16;
    const float* qp = qpart + (row0 + r) * 64 + c16;
#pragma unroll
    for (int m = 0; m < 4; ++m) {
      const int c = c16 + 4 * m;
      float4 v = *(const float4*)(qp + 4 * m);
      qs[r * 69 + c + 0] = tanhf(v.x + b1[c + 0]);
      qs[r * 69 + c + 1] = tanhf(v.y + b1[c + 1]);
      qs[r * 69 + c + 2] = tanhf(v.z + b1[c + 2]);
      qs[r * 69 + c + 3] = tanhf(v.w + b1[c + 3]);
    }
  }
  __syncthreads();
  if (tid < 64) {
    const int r = tid;
    ushortT* frow = featsb + (row0 + r) * 128;
    const float PI_F = 3.14159274101257324f;
    const float IS2 = 0.707106769084930420f;
    bool swp = false;
    for (int j = 0; j < 32; ++j) {
      float th = qs[r * 69 + 2 * j] * PI_F;
      float ph = qs[r * 69 + 2 * j + 1] * PI_F;
      float hf = 0.5f * th;
      float chf = cosf(hf), shf = sinf(hf);
      float cp = cosf(ph), sp = sinf(ph);
      float ar = chf, ai = 0.0f;
      float br = shf * cp, bi = shf * sp;
      if ((j & 1) == 0) {
        float t1r = (ar + br) * IS2, t1i = (ai + bi) * IS2;
        float t2r = (ar - br) * IS2, t2i = (ai - bi) * IS2;
        ar = t1r; ai = t1i; br = t2r; bi = t2i;
      }
      if (swp) { float t = ar; ar = br; br = t; t = ai; ai = bi; bi = t; }
      ushort4 o;
      o.x = f2b(ar); o.y = f2b(ai); o.z = f2b(br); o.w = f2b(bi);
      *(ushort4*)&frow[4 * j] = o;
      swp = sqrtf(fmaf(br, br, bi * bi)) > 0.5f;
    }
  }
}

// ---------------- K1b: analytic LN stats per row -> muinv (round-5 verbatim)
__global__ __launch_bounds__(256) void k1b(const ushortT* __restrict__ featsb,
                                           const float* __restrict__ G,
                                           const float* __restrict__ wbar,
                                           const float* __restrict__ hb,
                                           const float* __restrict__ scal,
                                           float2* __restrict__ muinv) {
  __shared__ float ftr[128 * 68];
  __shared__ float gbuf[32 * 128];
  __shared__ float e2red[64 * 4];
  const int tid = threadIdx.x;
  const size_t row0 = (size_t)blockIdx.x * 64;
  {
    const int r = tid >> 2;
    const int ks = (tid & 3) * 32;
    const ushortT* fp = featsb + (row0 + r) * 128 + ks;
#pragma unroll
    for (int i = 0; i < 4; ++i) {
      ushort4 u0 = *(const ushort4*)(fp + i * 8);
      ushort4 u1 = *(const ushort4*)(fp + i * 8 + 4);
      ftr[(ks + i * 8 + 0) * 68 + r] = b2f(u0.x);
      ftr[(ks + i * 8 + 1) * 68 + r] = b2f(u0.y);
      ftr[(ks + i * 8 + 2) * 68 + r] = b2f(u0.z);
      ftr[(ks + i * 8 + 3) * 68 + r] = b2f(u0.w);
      ftr[(ks + i * 8 + 4) * 68 + r] = b2f(u1.x);
      ftr[(ks + i * 8 + 5) * 68 + r] = b2f(u1.y);
      ftr[(ks + i * 8 + 6) * 68 + r] = b2f(u1.z);
      ftr[(ks + i * 8 + 7) * 68 + r] = b2f(u1.w);
    }
  }
  __syncthreads();
  const int sr = tid >> 2;
  const int sp = tid & 3;
  float e2p = 0.f, mup = 0.f, hbp = 0.f;
  for (int chk = 0; chk < 4; ++chk) {
    __syncthreads();
    {
      const int al = tid >> 3;
      const int bo = (tid & 7) * 16;
      const float* gp = G + (size_t)(chk * 32 + al) * 128 + bo;
#pragma unroll
      for (int j4 = 0; j4 < 4; ++j4)
        *(float4*)(gbuf + al * 128 + bo + j4 * 4) = *(const float4*)(gp + j4 * 4);
    }
    __syncthreads();
    float vacc[32];
#pragma unroll
    for (int i = 0; i < 32; ++i) vacc[i] = 0.f;
    for (int al = 0; al < 32; ++al) {
      const int a = chk * 32 + al;
      const float fa = ftr[a * 68 + sr];
      const float* grow = gbuf + al * 128 + sp * 32;
#pragma unroll
      for (int t8 = 0; t8 < 8; ++t8) {
        float4 gv = *(const float4*)(grow + t8 * 4);
        vacc[t8 * 4 + 0] = fmaf(fa, gv.x, vacc[t8 * 4 + 0]);
        vacc[t8 * 4 + 1] = fmaf(fa, gv.y, vacc[t8 * 4 + 1]);
        vacc[t8 * 4 + 2] = fmaf(fa, gv.z, vacc[t8 * 4 + 2]);
        vacc[t8 * 4 + 3] = fmaf(fa, gv.w, vacc[t8 * 4 + 3]);
      }
      if (sp == 0) { mup = fmaf(fa, wbar[a], mup); hbp = fmaf(fa, hb[a], hbp); }
    }
#pragma unroll
    for (int bl = 0; bl < 32; ++bl)
      e2p = fmaf(vacc[bl], ftr[(sp * 32 + bl) * 68 + sr], e2p);
  }
  e2red[sr * 4 + sp] = e2p;
  __syncthreads();
  if (sp == 0) {
    float e2 = e2red[sr * 4 + 0] + e2red[sr * 4 + 1] + e2red[sr * 4 + 2] + e2red[sr * 4 + 3];
    e2 = fmaf(2.0f, hbp, e2) + scal[1];
    const float mu = (mup + scal[0]) * (1.0f / D_DIM);
    const float var = e2 * (1.0f / D_DIM) - mu * mu;
    float2 mi2;
    mi2.x = mu;
    mi2.y = 1.0f / sqrtf(var + LN_EPS);
    muinv[row0 + sr] = mi2;
  }
}

// ---------------- K2: bf16 MFMA GEMM2 + LN + residual (round-5 verbatim)
__global__ __launch_bounds__(256) void k2(const ushortT* __restrict__ featsb,
                                          const ushortT* __restrict__ W2t,
                                          const float* __restrict__ b2,
                                          const float* __restrict__ gam,
                                          const float* __restrict__ bet,
                                          const float* __restrict__ x,
                                          const float2* __restrict__ muinv,
                                          float* __restrict__ out) {
  const int bid = blockIdx.x;
  const int swz = (bid & 7) * 512 + (bid >> 3);
  const int mblk = swz >> 5, nblk = swz & 31;
  const size_t row0 = (size_t)mblk * 128;
  const size_t col0 = (size_t)nblk * 128;
  const int tid = threadIdx.x;
  const int wid = tid >> 6, lane = tid & 63;
  const int wm = wid >> 1, wn = wid & 1;
  const int lr = lane & 15, lg = lane >> 4;
  f32x4 acc[4][4];
#pragma unroll
  for (int i = 0; i < 4; ++i)
#pragma unroll
    for (int j = 0; j < 4; ++j) acc[i][j] = (f32x4){0.f, 0.f, 0.f, 0.f};
  const ushortT* aBase = featsb + (row0 + wm * 64 + lr) * 128 + lg * 8;
  const ushortT* bBase = W2t + (col0 + wn * 64 + lr) * 128 + lg * 8;
#pragma unroll
  for (int ks = 0; ks < 4; ++ks) {
    bf16x8 a[4], b[4];
#pragma unroll
    for (int mi = 0; mi < 4; ++mi)
      a[mi] = *(const bf16x8*)(aBase + (size_t)mi * 16 * 128 + ks * 32);
#pragma unroll
    for (int ni = 0; ni < 4; ++ni)
      b[ni] = *(const bf16x8*)(bBase + (size_t)ni * 16 * 128 + ks * 32);
#pragma unroll
    for (int mi = 0; mi < 4; ++mi)
#pragma unroll
      for (int ni = 0; ni < 4; ++ni)
        acc[mi][ni] = __builtin_amdgcn_mfma_f32_16x16x32_bf16(a[mi], b[ni], acc[mi][ni], 0, 0, 0);
  }
  float b2c[4], gc[4], btc[4];
#pragma unroll
  for (int ni = 0; ni < 4; ++ni) {
    const size_t col = col0 + wn * 64 + ni * 16 + lr;
    b2c[ni] = b2[col];
    gc[ni] = gam[col];
    btc[ni] = bet[col];
  }
#pragma unroll
  for (int mi = 0; mi < 4; ++mi) {
#pragma unroll
    for (int j = 0; j < 4; ++j) {
      const size_t row = row0 + wm * 64 + mi * 16 + lg * 4 + j;
      const float2 mi2 = muinv[row];
      const float mu = mi2.x, inv = mi2.y;
      const float* xrow = x + row * D_DIM;
      float* orow = out + row * D_DIM;
#pragma unroll
      for (int ni = 0; ni < 4; ++ni) {
        const size_t col = col0 + wn * 64 + ni * 16 + lr;
        const float val = acc[mi][ni][j];
        const float y = fmaf((val + b2c[ni] - mu) * inv, gc[ni], btc[ni]) + xrow[col];
        orow[col] = y;
      }
    }
  }
}

extern "C" void kernel_launch(void* const* d_in, const int* in_sizes, int n_in,
                              void* d_out, int out_size, void* d_ws, size_t ws_size,
                              hipStream_t stream) {
  const float* x = (const float*)d_in[0];
  const float* W1 = (const float*)d_in[1];
  const float* b1 = (const float*)d_in[2];
  const float* W2 = (const float*)d_in[3];
  const float* b2 = (const float*)d_in[4];
  const float* gam = (const float*)d_in[5];
  const float* bet = (const float*)d_in[6];
  float* out = (float*)d_out;
  char* ws = (char*)d_ws;
  float* G = (float*)(ws + G_OFF);
  float* gpart = (float*)(ws + GPART_OFF);
  float* wbar = (float*)(ws + WBAR_OFF);
  float* hbv = (float*)(ws + HB_OFF);
  float* scal = (float*)(ws + SCAL_OFF);
  float2* muinv = (float2*)(ws + MUINV_OFF);
  float* qpart = (float*)(ws + FEATS_OFF);       // aliases featsb (row-aligned)
  ushortT* featsb = (ushortT*)(ws + FEATS_OFF);
  ushortT* W2t = (ushortT*)(ws + W2T_OFF);

  hipLaunchKernelGGL(k0a, dim3(64), dim3(256), 0, stream, W2, gpart);
  hipLaunchKernelGGL(k0b, dim3(64), dim3(256), 0, stream, gpart, G);
  hipLaunchKernelGGL(k0c, dim3(129), dim3(256), 0, stream, W2, b2, wbar, hbv, scal);
  hipLaunchKernelGGL(k0e, dim3(128), dim3(256), 0, stream, W2, W2t);
  hipLaunchKernelGGL(k1, dim3(1024), dim3(256), 0, stream, x, W1, qpart);
  hipLaunchKernelGGL(k1c, dim3(B_ROWS / 64), dim3(256), 0, stream, qpart, b1, featsb);
  hipLaunchKernelGGL(k1b, dim3(B_ROWS / 64), dim3(256), 0, stream,
                     featsb, G, wbar, hbv, scal, muinv);
  hipLaunchKernelGGL(k2, dim3(4096), dim3(256), 0, stream,
                     featsb, W2t, b2, gam, bet, x, muinv, out);
}

// Round 8
// 569.949 us; speedup vs baseline: 1.8752x; 1.6759x over previous
//
#include <hip/hip_runtime.h>
#include <hip/hip_bf16.h>
#include <math.h>

// ---------------------------------------------------------------------------
// Round 8: single delta vs round 7 (PASSED, 955us): k1b restructured to
// eliminate register spill (vacc[32] -> vacc[8]; 16 rows x 16 b-groups,
// 4 sequential row-chunks). Everything else round-7 verbatim.
//   Round-7 profile: k1b was 424-454us, VGPR=256, VALUBusy 1.4%,
//   ~1GB scratch HBM traffic => spill-bound. Logical work is ~15us.
// ws footprint: 6,489,120 B (proven-safe).
// ---------------------------------------------------------------------------

#define B_ROWS 16384
#define D_DIM  4096
#define LN_EPS 1e-5f

typedef unsigned short ushortT;
typedef short bf16x8 __attribute__((ext_vector_type(8)));
typedef float f32x4 __attribute__((ext_vector_type(4)));

// ---- ws byte offsets (== round 5/7 layout; qpart aliases feats) ----
#define G_OFF      0u           // 128*128 f32   = 65536
#define GPART_OFF  65536u       // 16*16384 f32  = 1048576 (dead after k0b)
#define WBAR_OFF   1114112u     // 128 f32
#define HB_OFF     1114624u     // 128 f32
#define SCAL_OFF   1115136u     // 8 f32
#define MUINV_OFF  1115168u     // 16384 float2  = 131072
#define FEATS_OFF  1246240u     // 16384 rows x 256B: qpart f32[64] -> bf16[128]
#define W2T_OFF    5440544u     // 4096*128 bf16  = 1048576
// total 6,489,120 B

__device__ __forceinline__ ushortT f2b(float v) {
  __hip_bfloat16 h = __float2bfloat16(v);
  return *(ushortT*)&h;
}
__device__ __forceinline__ float b2f(ushortT u) {
  __hip_bfloat16 h;
  *(ushortT*)&h = u;
  return __bfloat162float(h);
}
__device__ __forceinline__ float rndbf(float v) { return b2f(f2b(v)); }

#define FMA16(ACC, AV, BV)                                   \
  ACC[0][0] = fmaf(AV.x, BV.x, ACC[0][0]);                   \
  ACC[0][1] = fmaf(AV.x, BV.y, ACC[0][1]);                   \
  ACC[0][2] = fmaf(AV.x, BV.z, ACC[0][2]);                   \
  ACC[0][3] = fmaf(AV.x, BV.w, ACC[0][3]);                   \
  ACC[1][0] = fmaf(AV.y, BV.x, ACC[1][0]);                   \
  ACC[1][1] = fmaf(AV.y, BV.y, ACC[1][1]);                   \
  ACC[1][2] = fmaf(AV.y, BV.z, ACC[1][2]);                   \
  ACC[1][3] = fmaf(AV.y, BV.w, ACC[1][3]);                   \
  ACC[2][0] = fmaf(AV.z, BV.x, ACC[2][0]);                   \
  ACC[2][1] = fmaf(AV.z, BV.y, ACC[2][1]);                   \
  ACC[2][2] = fmaf(AV.z, BV.z, ACC[2][2]);                   \
  ACC[2][3] = fmaf(AV.z, BV.w, ACC[2][3]);                   \
  ACC[3][0] = fmaf(AV.w, BV.x, ACC[3][0]);                   \
  ACC[3][1] = fmaf(AV.w, BV.y, ACC[3][1]);                   \
  ACC[3][2] = fmaf(AV.w, BV.z, ACC[3][2]);                   \
  ACC[3][3] = fmaf(AV.w, BV.w, ACC[3][3]);

// ---------------- K0a: Gpart from bf16-rounded W2
__global__ __launch_bounds__(256) void k0a(const float* __restrict__ W2,
                                           float* __restrict__ gpart) {
  __shared__ float wbt[32][132];
  const int tid = threadIdx.x;
  const int ac = blockIdx.x & 3;
  const int kp = blockIdx.x >> 2;
  const int kbase = kp * 256;
  const int ag = tid >> 5, a0 = ag * 4;
  const int bg = tid & 31, b0 = bg * 4;
  const int sb = tid >> 1;
  const int sk = (tid & 1) * 16;
  float acc[4][4] = {};
  for (int sub = 0; sub < 8; ++sub) {
    const int k0 = kbase + sub * 32;
    const float* wp = W2 + (size_t)sb * D_DIM + k0 + sk;
#pragma unroll
    for (int j4 = 0; j4 < 4; ++j4) {
      float4 v = *(const float4*)(wp + j4 * 4);
      wbt[sk + j4 * 4 + 0][sb] = rndbf(v.x);
      wbt[sk + j4 * 4 + 1][sb] = rndbf(v.y);
      wbt[sk + j4 * 4 + 2][sb] = rndbf(v.z);
      wbt[sk + j4 * 4 + 3][sb] = rndbf(v.w);
    }
    __syncthreads();
#pragma unroll 8
    for (int k = 0; k < 32; ++k) {
      float4 av = *(const float4*)&wbt[k][ac * 32 + a0];
      float4 bv = *(const float4*)&wbt[k][b0];
      FMA16(acc, av, bv)
    }
    __syncthreads();
  }
  float* gp = gpart + (size_t)kp * 16384 + (size_t)(ac * 32 + a0) * 128 + b0;
#pragma unroll
  for (int i = 0; i < 4; ++i) {
    float4 v;
    v.x = acc[i][0]; v.y = acc[i][1]; v.z = acc[i][2]; v.w = acc[i][3];
    *(float4*)(gp + (size_t)i * 128) = v;
  }
}

// ---------------- K0b: reduce partials -> G
__global__ __launch_bounds__(256) void k0b(const float* __restrict__ gpart,
                                           float* __restrict__ G) {
  const int e = blockIdx.x * 256 + threadIdx.x;
  float s = 0.f;
#pragma unroll
  for (int p = 0; p < 16; ++p) s += gpart[(size_t)p * 16384 + e];
  G[e] = s;
}

// ---------------- K0c: wbar, hb (bf16-rounded W2), sumb, sum b2^2
__global__ __launch_bounds__(256) void k0c(const float* __restrict__ W2,
                                           const float* __restrict__ b2,
                                           float* __restrict__ wbar,
                                           float* __restrict__ hb,
                                           float* __restrict__ scal) {
  __shared__ float r1[256], r2[256];
  const int a = blockIdx.x, t = threadIdx.x;
  float s1 = 0.f, s2 = 0.f;
  if (a < 128) {
    const float* wp = W2 + (size_t)a * D_DIM;
    for (int j = t; j < D_DIM; j += 256) {
      float w = rndbf(wp[j]);
      s1 += w; s2 = fmaf(w, b2[j], s2);
    }
  } else {
    for (int j = t; j < D_DIM; j += 256) { float b = b2[j]; s1 += b; s2 = fmaf(b, b, s2); }
  }
  r1[t] = s1; r2[t] = s2;
  __syncthreads();
  for (int s = 128; s > 0; s >>= 1) {
    if (t < s) { r1[t] += r1[t + s]; r2[t] += r2[t + s]; }
    __syncthreads();
  }
  if (t == 0) {
    if (a < 128) { wbar[a] = r1[0]; hb[a] = r2[0]; }
    else         { scal[0] = r1[0]; scal[1] = r2[0]; }
  }
}

// ---------------- K0e: W2t[n][k] = bf16(W2[k][n])   (4096 x 128 bf16)
__global__ __launch_bounds__(256) void k0e(const float* __restrict__ W2,
                                           ushortT* __restrict__ W2t) {
  __shared__ ushortT tile[32][136];
  const int t = threadIdx.x;
  const int j0 = blockIdx.x * 32;
#pragma unroll
  for (int p = 0; p < 4; ++p) {
    const int a = p * 32 + (t >> 3);
    const int jc = (t & 7) * 4;
    float4 v = *(const float4*)&W2[(size_t)a * D_DIM + j0 + jc];
    tile[jc + 0][a] = f2b(v.x);
    tile[jc + 1][a] = f2b(v.y);
    tile[jc + 2][a] = f2b(v.z);
    tile[jc + 3][a] = f2b(v.w);
  }
  __syncthreads();
  const int j = t >> 3;
  const int a0 = (t & 7) * 16;
  uint4 u0 = *(const uint4*)&tile[j][a0];
  uint4 u1 = *(const uint4*)&tile[j][a0 + 8];
  *(uint4*)&W2t[(size_t)(j0 + j) * 128 + a0] = u0;
  *(uint4*)&W2t[(size_t)(j0 + j) * 128 + a0 + 8] = u1;
}

// ---------------- K1: f32 GEMM1, full-K ascending chain, TN=4, grid 1024
// (round-7 verbatim, validated)
__global__ __launch_bounds__(256) void k1(const float* __restrict__ x,
                                          const float* __restrict__ W1,
                                          float* __restrict__ qpart) {
  __shared__ float xs[64][65];   // [k][row]
  __shared__ float ws1[64][20];  // [k][16 cols + pad]
  const int tid = threadIdx.x;
  const int bid = blockIdx.x;    // 1024
  const int cb = (bid >> 3) & 3;
  const int rb = (bid & 7) | ((bid >> 5) << 3);
  const size_t row0 = (size_t)rb * 64;
  const int c16 = cb * 16;
  const int lane = tid & 63;
  const int w4 = (tid >> 6) * 4;
  const int sr = tid >> 2;          // staging row / k-row 0..63
  const int sq = (tid & 3) * 16;    // x staging k offset
  const int cq = (tid & 3) * 4;     // W1 staging col offset
  float acc[4] = {};
  float4 xr[4], wr;
  {
    const float* xp = x + (row0 + sr) * D_DIM + sq;
    xr[0] = *(const float4*)(xp);
    xr[1] = *(const float4*)(xp + 4);
    xr[2] = *(const float4*)(xp + 8);
    xr[3] = *(const float4*)(xp + 12);
    wr = *(const float4*)(W1 + (size_t)sr * 128 + c16 + cq);
  }
  for (int ch = 0; ch < 64; ++ch) {
    __syncthreads();  // previous chunk fully consumed
#pragma unroll
    for (int i = 0; i < 4; ++i) {
      xs[sq + i * 4 + 0][sr] = xr[i].x;
      xs[sq + i * 4 + 1][sr] = xr[i].y;
      xs[sq + i * 4 + 2][sr] = xr[i].z;
      xs[sq + i * 4 + 3][sr] = xr[i].w;
    }
    *(float4*)&ws1[sr][cq] = wr;
    __syncthreads();
    if (ch < 63) {
      const int kn = (ch + 1) * 64;
      const float* xp = x + (row0 + sr) * D_DIM + kn + sq;
      xr[0] = *(const float4*)(xp);
      xr[1] = *(const float4*)(xp + 4);
      xr[2] = *(const float4*)(xp + 8);
      xr[3] = *(const float4*)(xp + 12);
      wr = *(const float4*)(W1 + (size_t)(kn + sr) * 128 + c16 + cq);
    }
#pragma unroll 8
    for (int k = 0; k < 64; ++k) {
      const float xv = xs[k][lane];
      const float4 wv = *(const float4*)&ws1[k][w4];
      acc[0] = fmaf(xv, wv.x, acc[0]);
      acc[1] = fmaf(xv, wv.y, acc[1]);
      acc[2] = fmaf(xv, wv.z, acc[2]);
      acc[3] = fmaf(xv, wv.w, acc[3]);
    }
  }
  float4 v;
  v.x = acc[0]; v.y = acc[1]; v.z = acc[2]; v.w = acc[3];
  *(float4*)(qpart + (row0 + lane) * 64 + c16 + w4) = v;
}

// ---------------- K1c: tanh(acc+b1) + quantum circuit -> feats bf16
// (round-5/7 verbatim)
__global__ __launch_bounds__(256) void k1c(const float* __restrict__ qpart,
                                           const float* __restrict__ b1,
                                           ushortT* __restrict__ featsb) {
  __shared__ float qs[64 * 69];
  const int tid = threadIdx.x;
  const size_t row0 = (size_t)blockIdx.x * 64;
  {
    const int r = tid >> 2, c16 = (tid & 3) * 16;
    const float* qp = qpart + (row0 + r) * 64 + c16;
#pragma unroll
    for (int m = 0; m < 4; ++m) {
      const int c = c16 + 4 * m;
      float4 v = *(const float4*)(qp + 4 * m);
      qs[r * 69 + c + 0] = tanhf(v.x + b1[c + 0]);
      qs[r * 69 + c + 1] = tanhf(v.y + b1[c + 1]);
      qs[r * 69 + c + 2] = tanhf(v.z + b1[c + 2]);
      qs[r * 69 + c + 3] = tanhf(v.w + b1[c + 3]);
    }
  }
  __syncthreads();
  if (tid < 64) {
    const int r = tid;
    ushortT* frow = featsb + (row0 + r) * 128;
    const float PI_F = 3.14159274101257324f;
    const float IS2 = 0.707106769084930420f;
    bool swp = false;
    for (int j = 0; j < 32; ++j) {
      float th = qs[r * 69 + 2 * j] * PI_F;
      float ph = qs[r * 69 + 2 * j + 1] * PI_F;
      float hf = 0.5f * th;
      float chf = cosf(hf), shf = sinf(hf);
      float cp = cosf(ph), sp = sinf(ph);
      float ar = chf, ai = 0.0f;
      float br = shf * cp, bi = shf * sp;
      if ((j & 1) == 0) {
        float t1r = (ar + br) * IS2, t1i = (ai + bi) * IS2;
        float t2r = (ar - br) * IS2, t2i = (ai - bi) * IS2;
        ar = t1r; ai = t1i; br = t2r; bi = t2i;
      }
      if (swp) { float t = ar; ar = br; br = t; t = ai; ai = bi; bi = t; }
      ushort4 o;
      o.x = f2b(ar); o.y = f2b(ai); o.z = f2b(br); o.w = f2b(bi);
      *(ushort4*)&frow[4 * j] = o;
      swp = sqrtf(fmaf(br, br, bi * bi)) > 0.5f;
    }
  }
}

// ---------------- K1b (NEW, this round's single delta):
// analytic LN stats, spill-free: 16 rows x 16 b-groups per pass, vacc[8].
// e2(row) = f^T G f computed as: vacc[b] = sum_a f_a G[a][b] (8 b per thread),
// then e2p = sum_b vacc[b] f_b, reduced over 16 threads per row.
__global__ __launch_bounds__(256) void k1b(const ushortT* __restrict__ featsb,
                                           const float* __restrict__ G,
                                           const float* __restrict__ wbar,
                                           const float* __restrict__ hb,
                                           const float* __restrict__ scal,
                                           float2* __restrict__ muinv) {
  __shared__ float ftr[128 * 68];   // [feat][row] 34816 B
  __shared__ float gbuf[32 * 128];  // 16384 B
  __shared__ float e2red[64 * 17];  // 4352 B  [row][16 partials]
  const int tid = threadIdx.x;
  const size_t row0 = (size_t)blockIdx.x * 64;
  // stage feats (bf16 -> f32, transposed) -- validated staging pattern
  {
    const int r = tid >> 2;
    const int ks = (tid & 3) * 32;
    const ushortT* fp = featsb + (row0 + r) * 128 + ks;
#pragma unroll
    for (int i = 0; i < 4; ++i) {
      ushort4 u0 = *(const ushort4*)(fp + i * 8);
      ushort4 u1 = *(const ushort4*)(fp + i * 8 + 4);
      ftr[(ks + i * 8 + 0) * 68 + r] = b2f(u0.x);
      ftr[(ks + i * 8 + 1) * 68 + r] = b2f(u0.y);
      ftr[(ks + i * 8 + 2) * 68 + r] = b2f(u0.z);
      ftr[(ks + i * 8 + 3) * 68 + r] = b2f(u0.w);
      ftr[(ks + i * 8 + 4) * 68 + r] = b2f(u1.x);
      ftr[(ks + i * 8 + 5) * 68 + r] = b2f(u1.y);
      ftr[(ks + i * 8 + 6) * 68 + r] = b2f(u1.z);
      ftr[(ks + i * 8 + 7) * 68 + r] = b2f(u1.w);
    }
  }
  const int rloc = tid >> 4;       // 0..15 row within chunk
  const int bo = (tid & 15) * 8;   // 8 b-columns
  const int sal = tid >> 3;        // G staging: row 0..31
  const int sbo = (tid & 7) * 16;  // G staging: col offset
#pragma unroll 1
  for (int rchk = 0; rchk < 4; ++rchk) {
    const int r = rchk * 16 + rloc;
    float vacc[8] = {0.f, 0.f, 0.f, 0.f, 0.f, 0.f, 0.f, 0.f};
#pragma unroll 1
    for (int gchk = 0; gchk < 4; ++gchk) {
      __syncthreads();  // previous consumers of gbuf done (also covers ftr staging at rchk=0,gchk=0)
      {
        const float* gp = G + (size_t)(gchk * 32 + sal) * 128 + sbo;
#pragma unroll
        for (int j4 = 0; j4 < 4; ++j4)
          *(float4*)(gbuf + sal * 128 + sbo + j4 * 4) = *(const float4*)(gp + j4 * 4);
      }
      __syncthreads();
#pragma unroll 4
      for (int al = 0; al < 32; ++al) {
        const float fa = ftr[(gchk * 32 + al) * 68 + r];
        const float4 g0 = *(const float4*)&gbuf[al * 128 + bo];
        const float4 g1 = *(const float4*)&gbuf[al * 128 + bo + 4];
        vacc[0] = fmaf(fa, g0.x, vacc[0]);
        vacc[1] = fmaf(fa, g0.y, vacc[1]);
        vacc[2] = fmaf(fa, g0.z, vacc[2]);
        vacc[3] = fmaf(fa, g0.w, vacc[3]);
        vacc[4] = fmaf(fa, g1.x, vacc[4]);
        vacc[5] = fmaf(fa, g1.y, vacc[5]);
        vacc[6] = fmaf(fa, g1.z, vacc[6]);
        vacc[7] = fmaf(fa, g1.w, vacc[7]);
      }
    }
    float e2p = 0.f;
#pragma unroll
    for (int j = 0; j < 8; ++j)
      e2p = fmaf(vacc[j], ftr[(bo + j) * 68 + r], e2p);
    e2red[r * 17 + (tid & 15)] = e2p;
  }
  __syncthreads();
  if (tid < 64) {
    const int r = tid;
    float e2 = 0.f;
#pragma unroll
    for (int p = 0; p < 16; ++p) e2 += e2red[r * 17 + p];
    float mup = 0.f, hbp = 0.f;
#pragma unroll 4
    for (int a = 0; a < 128; ++a) {
      const float fa = ftr[a * 68 + r];
      mup = fmaf(fa, wbar[a], mup);
      hbp = fmaf(fa, hb[a], hbp);
    }
    e2 = fmaf(2.0f, hbp, e2) + scal[1];
    const float mu = (mup + scal[0]) * (1.0f / D_DIM);
    const float var = e2 * (1.0f / D_DIM) - mu * mu;
    float2 mi2;
    mi2.x = mu;
    mi2.y = 1.0f / sqrtf(var + LN_EPS);
    muinv[row0 + r] = mi2;
  }
}

// ---------------- K2: bf16 MFMA GEMM2 + LN + residual (round-5/7 verbatim)
__global__ __launch_bounds__(256) void k2(const ushortT* __restrict__ featsb,
                                          const ushortT* __restrict__ W2t,
                                          const float* __restrict__ b2,
                                          const float* __restrict__ gam,
                                          const float* __restrict__ bet,
                                          const float* __restrict__ x,
                                          const float2* __restrict__ muinv,
                                          float* __restrict__ out) {
  const int bid = blockIdx.x;
  const int swz = (bid & 7) * 512 + (bid >> 3);
  const int mblk = swz >> 5, nblk = swz & 31;
  const size_t row0 = (size_t)mblk * 128;
  const size_t col0 = (size_t)nblk * 128;
  const int tid = threadIdx.x;
  const int wid = tid >> 6, lane = tid & 63;
  const int wm = wid >> 1, wn = wid & 1;
  const int lr = lane & 15, lg = lane >> 4;
  f32x4 acc[4][4];
#pragma unroll
  for (int i = 0; i < 4; ++i)
#pragma unroll
    for (int j = 0; j < 4; ++j) acc[i][j] = (f32x4){0.f, 0.f, 0.f, 0.f};
  const ushortT* aBase = featsb + (row0 + wm * 64 + lr) * 128 + lg * 8;
  const ushortT* bBase = W2t + (col0 + wn * 64 + lr) * 128 + lg * 8;
#pragma unroll
  for (int ks = 0; ks < 4; ++ks) {
    bf16x8 a[4], b[4];
#pragma unroll
    for (int mi = 0; mi < 4; ++mi)
      a[mi] = *(const bf16x8*)(aBase + (size_t)mi * 16 * 128 + ks * 32);
#pragma unroll
    for (int ni = 0; ni < 4; ++ni)
      b[ni] = *(const bf16x8*)(bBase + (size_t)ni * 16 * 128 + ks * 32);
#pragma unroll
    for (int mi = 0; mi < 4; ++mi)
#pragma unroll
      for (int ni = 0; ni < 4; ++ni)
        acc[mi][ni] = __builtin_amdgcn_mfma_f32_16x16x32_bf16(a[mi], b[ni], acc[mi][ni], 0, 0, 0);
  }
  float b2c[4], gc[4], btc[4];
#pragma unroll
  for (int ni = 0; ni < 4; ++ni) {
    const size_t col = col0 + wn * 64 + ni * 16 + lr;
    b2c[ni] = b2[col];
    gc[ni] = gam[col];
    btc[ni] = bet[col];
  }
#pragma unroll
  for (int mi = 0; mi < 4; ++mi) {
#pragma unroll
    for (int j = 0; j < 4; ++j) {
      const size_t row = row0 + wm * 64 + mi * 16 + lg * 4 + j;
      const float2 mi2 = muinv[row];
      const float mu = mi2.x, inv = mi2.y;
      const float* xrow = x + row * D_DIM;
      float* orow = out + row * D_DIM;
#pragma unroll
      for (int ni = 0; ni < 4; ++ni) {
        const size_t col = col0 + wn * 64 + ni * 16 + lr;
        const float val = acc[mi][ni][j];
        const float y = fmaf((val + b2c[ni] - mu) * inv, gc[ni], btc[ni]) + xrow[col];
        orow[col] = y;
      }
    }
  }
}

extern "C" void kernel_launch(void* const* d_in, const int* in_sizes, int n_in,
                              void* d_out, int out_size, void* d_ws, size_t ws_size,
                              hipStream_t stream) {
  const float* x = (const float*)d_in[0];
  const float* W1 = (const float*)d_in[1];
  const float* b1 = (const float*)d_in[2];
  const float* W2 = (const float*)d_in[3];
  const float* b2 = (const float*)d_in[4];
  const float* gam = (const float*)d_in[5];
  const float* bet = (const float*)d_in[6];
  float* out = (float*)d_out;
  char* ws = (char*)d_ws;
  float* G = (float*)(ws + G_OFF);
  float* gpart = (float*)(ws + GPART_OFF);
  float* wbar = (float*)(ws + WBAR_OFF);
  float* hbv = (float*)(ws + HB_OFF);
  float* scal = (float*)(ws + SCAL_OFF);
  float2* muinv = (float2*)(ws + MUINV_OFF);
  float* qpart = (float*)(ws + FEATS_OFF);       // aliases featsb (row-aligned)
  ushortT* featsb = (ushortT*)(ws + FEATS_OFF);
  ushortT* W2t = (ushortT*)(ws + W2T_OFF);

  hipLaunchKernelGGL(k0a, dim3(64), dim3(256), 0, stream, W2, gpart);
  hipLaunchKernelGGL(k0b, dim3(64), dim3(256), 0, stream, gpart, G);
  hipLaunchKernelGGL(k0c, dim3(129), dim3(256), 0, stream, W2, b2, wbar, hbv, scal);
  hipLaunchKernelGGL(k0e, dim3(128), dim3(256), 0, stream, W2, W2t);
  hipLaunchKernelGGL(k1, dim3(1024), dim3(256), 0, stream, x, W1, qpart);
  hipLaunchKernelGGL(k1c, dim3(B_ROWS / 64), dim3(256), 0, stream, qpart, b1, featsb);
  hipLaunchKernelGGL(k1b, dim3(B_ROWS / 64), dim3(256), 0, stream,
                     featsb, G, wbar, hbv, scal, muinv);
  hipLaunchKernelGGL(k2, dim3(4096), dim3(256), 0, stream,
                     featsb, W2t, b2, gam, bet, x, muinv, out);
}